// Round 1
// baseline (11759.995 us; speedup 1.0000x reference)
//
#include <hip/hip_runtime.h>
#include <hip/hip_bf16.h>

#define NTOK  49      // WS*WS
#define CDIM  256
#define NHD   8
#define HDIM  32
#define HP    224
#define WPW   224
#define SHIFT 3

// LDS float-region layout (union of phases):
//   phase 1/2: x window [49][256] = 12544 floats
//   phase 3:   q[49*33] k[49*33] v[49*33] attn[2401] mask[2401] bias[1352]
#define Q_OFF   0      // 49*33 = 1617
#define K_OFF   1617
#define V_OFF   3234
#define ATT_OFF 4851   // 2401
#define MSK_OFF 7252   // 2401
#define BIA_OFF 9653   // 1352 -> total 11005 <= 12544

__global__ __launch_bounds__(256, 2)
void swin_attn_kernel(const float* __restrict__ x,
                      const float* __restrict__ mask,
                      const float* __restrict__ qkv_w,
                      const float* __restrict__ qkv_b,
                      const float* __restrict__ btab,
                      float* __restrict__ out)
{
    __shared__ __align__(16) float sm[12544];
    __shared__ int nsrc[NTOK];

    const int tid = threadIdx.x;
    const int blk = blockIdx.x;
    const int b   = blk >> 10;      // 1024 windows per batch
    const int wi  = blk & 1023;
    const int wh  = wi >> 5, ww = wi & 31;

    // source (== destination) token index per window row; roll folded in
    if (tid < NTOK) {
        int i = tid / 7, j = tid - i * 7;
        int hs = wh * 7 + i + SHIFT; if (hs >= HP)  hs -= HP;
        int wsx = ww * 7 + j + SHIFT; if (wsx >= WPW) wsx -= WPW;
        nsrc[tid] = hs * WPW + wsx;
    }
    __syncthreads();

    // ---- phase 1: stage x window into LDS (49 rows x 256 floats) ----
    const size_t xbase = (size_t)b * (HP * WPW) * CDIM;
    for (int idx = tid; idx < NTOK * 64; idx += 256) {
        int r = idx >> 6, c4 = idx & 63;
        ((float4*)sm)[idx] =
            *((const float4*)(x + xbase + (size_t)nsrc[r] * CDIM) + c4);
    }
    __syncthreads();

    // ---- phase 2: QKV GEMM. thread t = channel t of q,k,v for all 49 rows ----
    float accq[NTOK], acck[NTOK], accv[NTOK];
#pragma unroll
    for (int r = 0; r < NTOK; ++r) { accq[r] = 0.f; acck[r] = 0.f; accv[r] = 0.f; }

    const float4* wq = (const float4*)(qkv_w + (size_t)tid * CDIM);
    const float4* wk = (const float4*)(qkv_w + (size_t)(256 + tid) * CDIM);
    const float4* wv = (const float4*)(qkv_w + (size_t)(512 + tid) * CDIM);

    for (int k4 = 0; k4 < 64; ++k4) {
        float4 a  = wq[k4];
        float4 bb = wk[k4];
        float4 cc = wv[k4];
#pragma unroll
        for (int r = 0; r < NTOK; ++r) {
            float4 xv = ((const float4*)sm)[(r << 6) + k4];
            accq[r] = fmaf(xv.w, a.w,  fmaf(xv.z, a.z,  fmaf(xv.y, a.y,  fmaf(xv.x, a.x,  accq[r]))));
            acck[r] = fmaf(xv.w, bb.w, fmaf(xv.z, bb.z, fmaf(xv.y, bb.y, fmaf(xv.x, bb.x, acck[r]))));
            accv[r] = fmaf(xv.w, cc.w, fmaf(xv.z, cc.z, fmaf(xv.y, cc.y, fmaf(xv.x, cc.x, accv[r]))));
        }
    }
    __syncthreads();   // x region dead from here; reuse it

    // ---- stage mask window + rel-bias table into LDS ----
    for (int idx = tid; idx < 2401; idx += 256)
        sm[MSK_OFF + idx] = mask[(size_t)wi * 2401 + idx];
    for (int idx = tid; idx < 1352; idx += 256)
        sm[BIA_OFF + idx] = btab[idx];

    const float bq  = qkv_b[tid];
    const float bk2 = qkv_b[256 + tid];
    const float bv2 = qkv_b[512 + tid];
    const float scale = 0.17677669529663687f;  // 1/sqrt(32)
    const int myh = tid >> 5, myd = tid & 31;

    // ---- phase 3: per-head attention ----
    for (int h = 0; h < NHD; ++h) {
        if (myh == h) {
#pragma unroll
            for (int r = 0; r < NTOK; ++r) {
                sm[Q_OFF + r * 33 + myd] = accq[r] + bq;
                sm[K_OFF + r * 33 + myd] = acck[r] + bk2;
                sm[V_OFF + r * 33 + myd] = accv[r] + bv2;
            }
        }
        __syncthreads();

        // logits: 49x49, scaled, + rel bias + mask
        for (int idx = tid; idx < 2401; idx += 256) {
            int r = idx / 49, c = idx - r * 49;
            const float* qp = &sm[Q_OFF + r * 33];
            const float* kp = &sm[K_OFF + c * 33];
            float s0 = 0.f, s1 = 0.f, s2 = 0.f, s3 = 0.f;
#pragma unroll
            for (int d = 0; d < 32; d += 4) {
                s0 = fmaf(qp[d],     kp[d],     s0);
                s1 = fmaf(qp[d + 1], kp[d + 1], s1);
                s2 = fmaf(qp[d + 2], kp[d + 2], s2);
                s3 = fmaf(qp[d + 3], kp[d + 3], s3);
            }
            int i1 = r / 7, j1 = r - i1 * 7;
            int i2 = c / 7, j2 = c - i2 * 7;
            int bidx = (i1 - i2 + 6) * 13 + (j1 - j2 + 6);
            sm[ATT_OFF + idx] = (s0 + s1 + s2 + s3) * scale
                              + sm[BIA_OFF + bidx * 8 + h]
                              + sm[MSK_OFF + idx];
        }
        __syncthreads();

        // softmax: one thread per query row
        if (tid < NTOK) {
            float* row = &sm[ATT_OFF + tid * 49];
            float mx = -1e30f;
            for (int c = 0; c < NTOK; ++c) mx = fmaxf(mx, row[c]);
            float sum = 0.f;
            for (int c = 0; c < NTOK; ++c) {
                float e = __expf(row[c] - mx);
                row[c] = e;
                sum += e;
            }
            float inv = 1.0f / sum;
            for (int c = 0; c < NTOK; ++c) row[c] *= inv;
        }
        __syncthreads();

        // out = attn @ v, scatter straight to global
        for (int idx = tid; idx < NTOK * HDIM; idx += 256) {
            int r = idx >> 5, d = idx & 31;
            const float* ap = &sm[ATT_OFF + r * 49];
            const float* vp = &sm[V_OFF + d];
            float s0 = 0.f, s1 = 0.f, s2 = 0.f, s3 = 0.f;
            for (int c = 0; c < 48; c += 4) {
                s0 = fmaf(ap[c],     vp[c * 33],       s0);
                s1 = fmaf(ap[c + 1], vp[(c + 1) * 33], s1);
                s2 = fmaf(ap[c + 2], vp[(c + 2) * 33], s2);
                s3 = fmaf(ap[c + 3], vp[(c + 3) * 33], s3);
            }
            s0 = fmaf(ap[48], vp[48 * 33], s0);
            out[xbase + (size_t)nsrc[r] * CDIM + h * HDIM + d] = s0 + s1 + s2 + s3;
        }
        __syncthreads();   // before next head overwrites q/k/v/attn
    }
}

extern "C" void kernel_launch(void* const* d_in, const int* in_sizes, int n_in,
                              void* d_out, int out_size, void* d_ws, size_t ws_size,
                              hipStream_t stream) {
    const float* x      = (const float*)d_in[0];
    const float* mask   = (const float*)d_in[1];
    const float* qkv_w  = (const float*)d_in[2];
    const float* qkv_b  = (const float*)d_in[3];
    const float* btab   = (const float*)d_in[4];
    // d_in[5], d_in[6] are H, W (constants 224, hard-coded)
    float* out = (float*)d_out;

    swin_attn_kernel<<<dim3(4096), dim3(256), 0, stream>>>(
        x, mask, qkv_w, qkv_b, btab, out);
}

// Round 2
// 1915.128 us; speedup vs baseline: 6.1406x; 6.1406x over previous
//
#include <hip/hip_runtime.h>
#include <hip/hip_bf16.h>

#define NTOK  49
#define CDIM  256
#define NHD   8
#define HDIM  32
#define HP    224
#define WPW   224
#define SHIFT 3

typedef __attribute__((ext_vector_type(8))) short short8;
typedef __attribute__((ext_vector_type(4))) short short4v;
typedef __attribute__((ext_vector_type(4))) float float4v;

static __device__ __forceinline__ short f2bf(float f) {
    unsigned u = __float_as_uint(f);
    u += 0x7FFF + ((u >> 16) & 1);          // round-to-nearest-even
    return (short)(u >> 16);
}

// ---------- pre-kernel: qkv_w fp32 -> bf16 row-major in workspace ----------
__global__ void cvt_w_kernel(const float* __restrict__ w, short* __restrict__ wb) {
    int t = blockIdx.x * 256 + threadIdx.x;     // 49152 threads, 4 elems each
    float4v f = *(const float4v*)(w + (size_t)t * 4);
    short4v o;
    o.x = f2bf(f.x); o.y = f2bf(f.y); o.z = f2bf(f.z); o.w = f2bf(f.w);
    *(short4v*)(wb + (size_t)t * 4) = o;
}

// ---------- fused swin attention ----------
// LDS: xs bf16 [8 kt][49 m][40]  (A-fragments: ds_read_b128, 80B row stride)
//      q/k/v fp32 [49][36], attn fp32 [49][50], nsrc[49]
struct SM {
    short xs[8 * 49 * 40];     // 31360 B
    float q[49 * 36];          // 7056 B
    float k[49 * 36];
    float v[49 * 36];
    float attn[49 * 50];       // 9800 B
    int   nsrc[49];
};                             // total 62524 B

__global__ __launch_bounds__(256, 2)
void swin_attn_kernel(const float* __restrict__ x,
                      const float* __restrict__ mask,
                      const float* __restrict__ qkv_b,
                      const float* __restrict__ btab,
                      const short* __restrict__ wb,
                      float* __restrict__ out)
{
    __shared__ __align__(16) SM S;

    const int tid = threadIdx.x;
    const int blk = blockIdx.x;
    const int b   = blk >> 10;
    const int wi  = blk & 1023;
    const int wh  = wi >> 5, ww = wi & 31;

    if (tid < NTOK) {
        int i = tid / 7, j = tid - i * 7;
        int hs = wh * 7 + i + SHIFT;  if (hs >= HP)  hs -= HP;
        int wsx = ww * 7 + j + SHIFT; if (wsx >= WPW) wsx -= WPW;
        S.nsrc[tid] = hs * WPW + wsx;
    }
    __syncthreads();

    // ---- stage x window as bf16 A-fragments ----
    const size_t xbase = (size_t)b * (HP * WPW) * CDIM;
    for (int idx = tid; idx < NTOK * 64; idx += 256) {
        int r = idx >> 6, k4 = idx & 63;
        float4v f = *(const float4v*)(x + xbase + (size_t)S.nsrc[r] * CDIM + k4 * 4);
        short4v o;
        o.x = f2bf(f.x); o.y = f2bf(f.y); o.z = f2bf(f.z); o.w = f2bf(f.w);
        int kt = k4 >> 3, kk = (k4 & 7) * 4;
        *(short4v*)&S.xs[(kt * 49 + r) * 40 + kk] = o;
    }
    __syncthreads();

    const int lane = tid & 63;
    const int w    = tid >> 6;
    const int n16  = lane & 15;
    const int quad = lane >> 4;
    const int m16  = lane & 15;

    // wave -> N-tile assignment: w0:{0,1} w1:{2,3} w2:{4} w3:{5}
    const int ncnt = (w < 2) ? 2 : 1;
    const int ntb  = (w < 2) ? 2 * w : w + 2;

    const float scale = 0.17677669529663687f;   // 1/sqrt(32)
    const float* maskp = mask + (size_t)wi * 2401;

    for (int h = 0; h < NHD; ++h) {
        // ---- QKV GEMM for head h: [64x256] @ [256x96] via MFMA ----
        int   seg[2], colb[2];
        const short* bptr[2];
        float bias[2];
        for (int i = 0; i < ncnt; ++i) {
            int j0 = (ntb + i) * 16;
            seg[i]  = j0 >> 5;
            colb[i] = j0 & 31;
            int chan = seg[i] * 256 + h * 32 + colb[i] + n16;
            bptr[i] = wb + (size_t)chan * 256 + quad * 8;
            bias[i] = qkv_b[chan];
        }

        float4v acc[4][2];
#pragma unroll
        for (int mt = 0; mt < 4; ++mt)
            for (int i = 0; i < 2; ++i)
                acc[mt][i] = (float4v)0.0f;

        for (int kt = 0; kt < 8; ++kt) {
            short8 a[4];
#pragma unroll
            for (int mt = 0; mt < 4; ++mt)
                a[mt] = *(const short8*)&S.xs[(kt * 49 + mt * 16 + m16) * 40 + quad * 8];
            for (int i = 0; i < ncnt; ++i) {
                short8 bf = *(const short8*)(bptr[i] + kt * 32);
#pragma unroll
                for (int mt = 0; mt < 4; ++mt)
                    acc[mt][i] = __builtin_amdgcn_mfma_f32_16x16x32_bf16(a[mt], bf, acc[mt][i], 0, 0, 0);
            }
        }

        // epilogue: D[r][c] -> q/k/v LDS (+bias); r = mt*16 + quad*4 + reg
        for (int i = 0; i < ncnt; ++i) {
            float* dst = (seg[i] == 0) ? S.q : (seg[i] == 1) ? S.k : S.v;
            int col = colb[i] + n16;
#pragma unroll
            for (int mt = 0; mt < 4; ++mt) {
#pragma unroll
                for (int reg = 0; reg < 4; ++reg) {
                    int r = mt * 16 + quad * 4 + reg;
                    if (r < NTOK) dst[r * 36 + col] = acc[mt][i][reg] + bias[i];
                }
            }
        }
        __syncthreads();

        // ---- logits: 4-row register tiling, float4 LDS reads ----
        for (int u = tid; u < 13 * 49; u += 256) {
            int rg = u / 49, c = u - rg * 49;
            int r0 = rg * 4;
            int nr = (r0 + 4 <= NTOK) ? 4 : (NTOK - r0);
            float4v kf[8];
#pragma unroll
            for (int d = 0; d < 8; ++d)
                kf[d] = *(const float4v*)&S.k[c * 36 + d * 4];
            int i2 = c / 7, j2 = c - i2 * 7;
            for (int rr = 0; rr < nr; ++rr) {
                int r = r0 + rr;
                float4v s = (float4v)0.0f;
#pragma unroll
                for (int d = 0; d < 8; ++d) {
                    float4v qv = *(const float4v*)&S.q[r * 36 + d * 4];
                    s += qv * kf[d];
                }
                int i1 = r / 7, j1 = r - i1 * 7;
                int bidx = (i1 - i2 + 6) * 13 + (j1 - j2 + 6);
                S.attn[r * 50 + c] = (s.x + s.y + s.z + s.w) * scale
                                   + btab[bidx * 8 + h]
                                   + maskp[r * 49 + c];
            }
        }
        __syncthreads();

        // ---- softmax, one thread per row ----
        if (tid < NTOK) {
            float* row = &S.attn[tid * 50];
            float mx = -1e30f;
            for (int c = 0; c < NTOK; ++c) mx = fmaxf(mx, row[c]);
            float sum = 0.f;
            for (int c = 0; c < NTOK; ++c) {
                float e = __expf(row[c] - mx);
                row[c] = e; sum += e;
            }
            float inv = 1.0f / sum;
            for (int c = 0; c < NTOK; ++c) row[c] *= inv;
        }
        __syncthreads();

        // ---- out = attn @ v : 2 rows x 4 dims per thread ----
        if (tid < 200) {
            int rg2 = tid >> 3, d4 = tid & 7;
            int r0 = rg2 * 2, r1 = r0 + 1;
            bool has1 = (r1 < NTOK);
            float4v o0 = (float4v)0.0f, o1 = (float4v)0.0f;
            for (int c = 0; c < NTOK; ++c) {
                float4v vv = *(const float4v*)&S.v[c * 36 + d4 * 4];
                float a0 = S.attn[r0 * 50 + c];
                o0 += a0 * vv;
                if (has1) {
                    float a1 = S.attn[r1 * 50 + c];
                    o1 += a1 * vv;
                }
            }
            *(float4v*)(out + xbase + (size_t)S.nsrc[r0] * CDIM + h * HDIM + d4 * 4) = o0;
            if (has1)
                *(float4v*)(out + xbase + (size_t)S.nsrc[r1] * CDIM + h * HDIM + d4 * 4) = o1;
        }
        __syncthreads();
    }
}

extern "C" void kernel_launch(void* const* d_in, const int* in_sizes, int n_in,
                              void* d_out, int out_size, void* d_ws, size_t ws_size,
                              hipStream_t stream) {
    const float* x      = (const float*)d_in[0];
    const float* mask   = (const float*)d_in[1];
    const float* qkv_w  = (const float*)d_in[2];
    const float* qkv_b  = (const float*)d_in[3];
    const float* btab   = (const float*)d_in[4];
    float* out = (float*)d_out;
    short* wb  = (short*)d_ws;                 // 768*256 bf16 = 384 KB

    cvt_w_kernel<<<dim3(192), dim3(256), 0, stream>>>(qkv_w, wb);
    swin_attn_kernel<<<dim3(4096), dim3(256), 0, stream>>>(
        x, mask, qkv_b, btab, wb, out);
}